// Round 1
// baseline (6204.384 us; speedup 1.0000x reference)
//
#include <hip/hip_runtime.h>
#include <math.h>

// MD-LSTM, 32x32 grid, B=128, HID=256, gates=1024.
// Diagonal wavefront: 63 launches; cells on diag d depend only on diag d-1.
// State in ping-pong buffers hbuf/sbuf[2][32][B][HID] in d_ws (16 MB).
// Validity of neighbor slots is exactly r>0 / c>0 -> no zero-init needed.

#define HIMG 32
#define WIMG 32
#define BATCH 128
#define HID 256

#define BM 64   // batch tile
#define BN 32   // k (per-gate hidden) tile
#define BK 32   // K chunk

#define SLAB (32 * 128 * 256)   // one diagonal's state: 32 slots x B x HID

__device__ __forceinline__ float sigmoid_(float xv) {
    // safe for large |x|: exp(-x) -> 0 or inf, both give finite result
    return 1.0f / (1.0f + __expf(-xv));
}
__device__ __forceinline__ float tanh_safe(float xv) {
    // tanh(x) = sign(x) * (1 - 2/(exp(2|x|)+1)); exp arg >= 0 so no inf/inf NaN
    float ax = fabsf(xv);
    float e = __expf(2.0f * ax);
    float t = 1.0f - 2.0f / (e + 1.0f);
    return copysignf(t, xv);
}

__global__ __launch_bounds__(256, 2)
void mdlstm_diag_kernel(const float* __restrict__ x,
                        const float* __restrict__ wih,
                        const float* __restrict__ whh,
                        const float* __restrict__ bias,
                        float* __restrict__ out,
                        float* __restrict__ hbuf,   // [2][32][128][256]
                        float* __restrict__ sbuf,   // [2][32][128][256]
                        int d, int rlo)
{
    // LDS: A = hsum tile [BM][BK] (row-major, stride 32);
    // W as [tgroup(8)][g*32+j (128)][4] -> all b128 accesses conflict-free.
    __shared__ float A_lds[BM * BK];        // 8 KB
    __shared__ float W_lds[8 * 128 * 4];    // 16 KB

    const int tid = threadIdx.x;
    const int r = rlo + blockIdx.y;
    const int c = d - r;
    const int b0 = (blockIdx.x & 1) * BM;
    const int k0 = (blockIdx.x >> 1) * BN;

    const int prev = (d & 1) ^ 1;
    const int cur  = d & 1;
    const float* hp = hbuf + prev * SLAB;
    const float* sp = sbuf + prev * SLAB;
    float* hc = hbuf + cur * SLAB;
    float* sc = sbuf + cur * SLAB;

    const bool has_up   = (r > 0);
    const bool has_left = (c > 0);
    const float* hu = hp + (r - 1) * (BATCH * HID);  // valid iff has_up
    const float* hl = hp + r * (BATCH * HID);        // valid iff has_left

    const int tx = tid & 31;   // k within tile
    const int ty = tid >> 5;   // 0..7

    float acc[4][8];
    #pragma unroll
    for (int g = 0; g < 4; g++)
        #pragma unroll
        for (int i = 0; i < 8; i++) acc[g][i] = 0.0f;

    for (int kk = 0; kk < HID; kk += BK) {
        // ---- stage A = h_up + h_left tile: 64x32 floats = 512 float4 ----
        #pragma unroll
        for (int p = 0; p < 2; p++) {
            int f = tid + p * 256;              // 0..511
            int bl = f >> 3;                    // 0..63
            int t4 = (f & 7) << 2;              // 0,4,..,28
            int ga = (b0 + bl) * HID + kk + t4;
            float4 va = has_up ? *(const float4*)(hu + ga) : make_float4(0.f, 0.f, 0.f, 0.f);
            if (has_left) {
                float4 vl = *(const float4*)(hl + ga);
                va.x += vl.x; va.y += vl.y; va.z += vl.z; va.w += vl.w;
            }
            *(float4*)&A_lds[bl * BK + t4] = va;
        }
        // ---- stage W: 4 gates x 32 rows x 32 t = 1024 float4 ----
        #pragma unroll
        for (int p = 0; p < 4; p++) {
            int f = tid + p * 256;              // 0..1023
            int row = f >> 3;                   // 0..127 = g*32 + j
            int t4 = (f & 7) << 2;
            int g = row >> 5;
            int j = row & 31;
            float4 vw = *(const float4*)(whh + (g * 256 + k0 + j) * HID + kk + t4);
            *(float4*)&W_lds[((t4 >> 2) * 128 + row) * 4] = vw;
        }
        __syncthreads();

        // ---- compute: per t-group, 12 b128 LDS reads for 128 FMAs ----
        #pragma unroll
        for (int tg = 0; tg < 8; tg++) {
            float4 w[4];
            #pragma unroll
            for (int g = 0; g < 4; g++)
                w[g] = *(const float4*)&W_lds[(tg * 128 + g * 32 + tx) * 4];
            #pragma unroll
            for (int i = 0; i < 8; i++) {
                int bl = ty + 8 * i;
                float4 a = *(const float4*)&A_lds[bl * BK + tg * 4];
                #pragma unroll
                for (int g = 0; g < 4; g++) {
                    acc[g][i] += a.x * w[g].x + a.y * w[g].y
                               + a.z * w[g].z + a.w * w[g].w;
                }
            }
        }
        __syncthreads();
    }

    // ---- fused epilogue: gates -> (h, s), write out/hbuf/sbuf ----
    const int k = k0 + tx;
    float wv[4], bv[4];
    #pragma unroll
    for (int g = 0; g < 4; g++) {
        wv[g] = wih[g * 256 + k];
        bv[g] = bias[g * 256 + k];
    }
    const int rc = r * WIMG + c;
    #pragma unroll
    for (int i = 0; i < 8; i++) {
        const int bl = ty + 8 * i;
        const int b = b0 + bl;
        const float xp = x[b * (HIMG * WIMG) + rc];
        float gi = acc[0][i] + xp * wv[0] + bv[0];
        float gf = acc[1][i] + xp * wv[1] + bv[1];
        float gg = acc[2][i] + xp * wv[2] + bv[2];
        float go = acc[3][i] + xp * wv[3] + bv[3];
        float iv = sigmoid_(gi);
        float fv = sigmoid_(gf);
        float gv = tanh_safe(gg);
        float ov = sigmoid_(go);
        float sin_ = 0.0f;
        if (has_up)   sin_ += sp[(r - 1) * (BATCH * HID) + b * HID + k];
        if (has_left) sin_ += sp[r * (BATCH * HID) + b * HID + k];
        float sv = fv * sin_ + iv * gv;
        float hv = ov * tanh_safe(sv);
        sc[r * (BATCH * HID) + b * HID + k] = sv;
        hc[r * (BATCH * HID) + b * HID + k] = hv;
        out[(size_t)b * (HIMG * WIMG * HID) + (size_t)rc * HID + k] = hv;
    }
}

extern "C" void kernel_launch(void* const* d_in, const int* in_sizes, int n_in,
                              void* d_out, int out_size, void* d_ws, size_t ws_size,
                              hipStream_t stream) {
    const float* x    = (const float*)d_in[0];   // (128, 1024)
    const float* wih  = (const float*)d_in[1];   // (1024, 1)
    const float* whh  = (const float*)d_in[2];   // (1024, 256)
    const float* bias = (const float*)d_in[3];   // (1024,)
    float* out = (float*)d_out;                  // (128, 32*32*256)

    float* hbuf = (float*)d_ws;                  // [2][32][128][256] = 8 MB
    float* sbuf = hbuf + 2 * SLAB;               // another 8 MB

    for (int d = 0; d < HIMG + WIMG - 1; d++) {
        int rlo = d - (WIMG - 1); if (rlo < 0) rlo = 0;
        int rhi = d < (HIMG - 1) ? d : (HIMG - 1);
        int nc = rhi - rlo + 1;
        dim3 grid(16, nc);   // 2 b-tiles x 8 k-tiles per cell
        mdlstm_diag_kernel<<<grid, 256, 0, stream>>>(x, wih, whh, bias, out,
                                                     hbuf, sbuf, d, rlo);
    }
}

// Round 3
// 3582.889 us; speedup vs baseline: 1.7317x; 1.7317x over previous
//
#include <hip/hip_runtime.h>
#include <math.h>

// MD-LSTM, 32x32 grid, B=128, HID=256, gates=1024.
// Diagonal wavefront: 63 launches; cells on diag d depend only on diag d-1.
//
// ACCURACY STRATEGY: the 63-step recurrence is chaotic — fp32 trajectories
// diverge ~2e-2 from any differently-ordered fp32 reference (R1=1.86e-2
// passed, R2=2.25e-2 failed; threshold 1.945e-2). So the WHOLE recurrence
// runs in fp64: state (h,s) stored as double, GEMM accumulated in double,
// nonlinearities in double libm. Weights stay fp32 (given data, exact when
// widened). fp64 trajectory ~= ideal trajectory => error vs harness ref is
// the ref's own rounding, not ours.
//
// State ping-pong hbuf/sbuf[2][32][B][HID] doubles in d_ws (33.6 MB).
// Neighbor validity == r>0 / c>0, so no zero-init of state needed.
//
// Work item: (cell, b-quarter(32), k-tile(32 gate cols x 4 gates)).
// id%8 == ktile -> round-robin block->XCD gives each XCD a fixed W slice
// (persistent L2 residency across the 63 launches).

#define HIMG 32
#define WIMG 32
#define BATCH 128
#define HID 256
#define BH (BATCH * HID)
#define SLAB (32 * 128 * 256)

#define WSTRIDE 516  // skew: +4 floats per t-group kills W staging-write bank conflicts

__global__ __launch_bounds__(256, 4)
void mdlstm_diag_kernel(const float* __restrict__ x,
                        const float* __restrict__ wih,
                        const float* __restrict__ whh,
                        const float* __restrict__ bias,
                        float* __restrict__ out,
                        double* __restrict__ hbuf,   // [2][32][128][256]
                        double* __restrict__ sbuf,   // [2][32][128][256]
                        int d, int rlo)
{
    __shared__ double A_lds[1024];        // 8 KB   flat [bl*32 + k]
    __shared__ float  W_lds[8 * WSTRIDE]; // 16.1 KB  [tg*516 + row*4 + e]

    const int tid = threadIdx.x;
    const int id  = blockIdx.x;
    const int cellIdx = id >> 5;
    const int tileIdx = id & 31;
    const int ktile = tileIdx & 7;        // == id % 8 -> XCD-stable W slice
    const int b4    = tileIdx >> 3;
    const int k0 = ktile * 32;
    const int b0 = b4 * 32;

    const int r = rlo + cellIdx;
    const int c = d - r;
    const int rc = r * WIMG + c;

    const int prev = (d & 1) ^ 1;
    const int cur  = d & 1;
    const double* hp = hbuf + (size_t)prev * SLAB;
    const double* sp = sbuf + (size_t)prev * SLAB;
    double* hc = hbuf + (size_t)cur * SLAB;
    double* sc = sbuf + (size_t)cur * SLAB;

    const bool has_up   = (r > 0);
    const bool has_left = (c > 0);
    const double* hu = hp + (size_t)(r - 1) * BH;  // valid iff has_up
    const double* hl = hp + (size_t)r * BH;        // valid iff has_left

    const int tx = tid & 31;              // k within tile
    const int ty = tid >> 5;              // 0..7

    // ---- staging coords ----
    // A: thread stages doubles {2*tid,2*tid+1} and {512+2*tid,+1}
    //    => (bl = tid>>4, k = (tid&15)*2) and (bl+16, same k). Contiguous LDS writes.
    const int a_bl = tid >> 4;
    const int a_k  = (tid & 15) * 2;
    const size_t ga0 = (size_t)(b0 + a_bl) * HID + a_k;
    const size_t ga1 = ga0 + (size_t)16 * HID;
    // W: p in 0..3: f=tid+p*256; row=f>>3 (0..127=g*32+j), tg=f&7 (k-group)
    const float* w_src[4];
    #pragma unroll
    for (int p = 0; p < 4; p++) {
        int f = tid + p * 256;
        int row = f >> 3;
        int g = row >> 5, j = row & 31;
        w_src[p] = whh + (size_t)(g * 256 + k0 + j) * HID + (f & 7) * 4;
    }

    double acc[4][4];
    #pragma unroll
    for (int g = 0; g < 4; g++)
        #pragma unroll
        for (int i = 0; i < 4; i++) acc[g][i] = 0.0;

    // ---- prefetch chunk 0 ----
    double2 pu0, pl0, pu1, pl1;
    float4 pw[4];
    {
        const double2 z = {0.0, 0.0};
        pu0 = has_up   ? *(const double2*)(hu + ga0) : z;
        pu1 = has_up   ? *(const double2*)(hu + ga1) : z;
        pl0 = has_left ? *(const double2*)(hl + ga0) : z;
        pl1 = has_left ? *(const double2*)(hl + ga1) : z;
        #pragma unroll
        for (int p = 0; p < 4; p++)
            pw[p] = *(const float4*)(w_src[p]);
    }

    for (int ck = 0; ck < 8; ck++) {
        __syncthreads();                  // previous compute done reading LDS
        double2 s0, s1;
        s0.x = pu0.x + pl0.x; s0.y = pu0.y + pl0.y;
        s1.x = pu1.x + pl1.x; s1.y = pu1.y + pl1.y;
        *(double2*)&A_lds[2 * tid] = s0;
        *(double2*)&A_lds[512 + 2 * tid] = s1;
        #pragma unroll
        for (int p = 0; p < 4; p++) {
            int f = tid + p * 256;
            *(float4*)&W_lds[(f & 7) * WSTRIDE + (f >> 3) * 4] = pw[p];
        }
        __syncthreads();                  // LDS ready

        if (ck < 7) {                     // prefetch next chunk during compute
            const int kk = (ck + 1) * 32;
            const double2 z = {0.0, 0.0};
            pu0 = has_up   ? *(const double2*)(hu + ga0 + kk) : z;
            pu1 = has_up   ? *(const double2*)(hu + ga1 + kk) : z;
            pl0 = has_left ? *(const double2*)(hl + ga0 + kk) : z;
            pl1 = has_left ? *(const double2*)(hl + ga1 + kk) : z;
            #pragma unroll
            for (int p = 0; p < 4; p++)
                pw[p] = *(const float4*)(w_src[p] + kk);
        }

        #pragma unroll
        for (int tg = 0; tg < 8; tg++) {
            double2 ad[4][2];
            #pragma unroll
            for (int i = 0; i < 4; i++) {
                const int bl = ty + 8 * i;
                ad[i][0] = *(const double2*)&A_lds[bl * 32 + tg * 4];
                ad[i][1] = *(const double2*)&A_lds[bl * 32 + tg * 4 + 2];
            }
            #pragma unroll
            for (int g = 0; g < 4; g++) {
                const float4 wf = *(const float4*)&W_lds[tg * WSTRIDE + (g * 32 + tx) * 4];
                const double w0 = (double)wf.x, w1 = (double)wf.y;
                const double w2 = (double)wf.z, w3 = (double)wf.w;
                #pragma unroll
                for (int i = 0; i < 4; i++) {
                    double t = acc[g][i];
                    t = fma(ad[i][0].x, w0, t);
                    t = fma(ad[i][0].y, w1, t);
                    t = fma(ad[i][1].x, w2, t);
                    t = fma(ad[i][1].y, w3, t);
                    acc[g][i] = t;
                }
            }
        }
    }

    // ---- fused epilogue (all fp64) ----
    const int k = k0 + tx;
    double wv[4], bv[4];
    #pragma unroll
    for (int g = 0; g < 4; g++) {
        wv[g] = (double)wih[g * 256 + k];
        bv[g] = (double)bias[g * 256 + k];
    }
    #pragma unroll
    for (int i = 0; i < 4; i++) {
        const int b = b0 + ty + 8 * i;
        const double xp = (double)x[b * (HIMG * WIMG) + rc];
        const double su = has_up   ? sp[(size_t)(r - 1) * BH + b * HID + k] : 0.0;
        const double sl = has_left ? sp[(size_t)r * BH + b * HID + k]       : 0.0;
        const double gi = acc[0][i] + xp * wv[0] + bv[0];
        const double gf = acc[1][i] + xp * wv[1] + bv[1];
        const double gg = acc[2][i] + xp * wv[2] + bv[2];
        const double go = acc[3][i] + xp * wv[3] + bv[3];
        const double iv = 1.0 / (1.0 + exp(-gi));
        const double fv = 1.0 / (1.0 + exp(-gf));
        const double gv = tanh(gg);
        const double ov = 1.0 / (1.0 + exp(-go));
        const double sv = fv * (su + sl) + iv * gv;
        const double hv = ov * tanh(sv);
        sc[(size_t)r * BH + b * HID + k] = sv;
        hc[(size_t)r * BH + b * HID + k] = hv;
        out[(size_t)b * (HIMG * WIMG * HID) + (size_t)rc * HID + k] = (float)hv;
    }
}

extern "C" void kernel_launch(void* const* d_in, const int* in_sizes, int n_in,
                              void* d_out, int out_size, void* d_ws, size_t ws_size,
                              hipStream_t stream) {
    const float* x    = (const float*)d_in[0];   // (128, 1024)
    const float* wih  = (const float*)d_in[1];   // (1024, 1)
    const float* whh  = (const float*)d_in[2];   // (1024, 256)
    const float* bias = (const float*)d_in[3];   // (1024,)
    float* out = (float*)d_out;                  // (128, 32*32*256)

    double* hbuf = (double*)d_ws;                // [2][32][128][256] dbl = 16.8 MB
    double* sbuf = hbuf + (size_t)2 * SLAB;      // 16.8 MB  (ws usage ~33.6 MB)

    for (int d = 0; d < HIMG + WIMG - 1; d++) {
        int rlo = d - (WIMG - 1); if (rlo < 0) rlo = 0;
        int rhi = d < (HIMG - 1) ? d : (HIMG - 1);
        int nc = rhi - rlo + 1;
        mdlstm_diag_kernel<<<dim3(nc * 32), 256, 0, stream>>>(
            x, wih, whh, bias, out, hbuf, sbuf, d, rlo);
    }
}